// Round 11
// baseline (1024.805 us; speedup 1.0000x reference)
//
#include <hip/hip_runtime.h>
#include <hip/hip_bf16.h>
#include <math.h>

#define BT 4096      // B*T tokens
#define HD 1024      // hidden
#define NHEAD 16
#define DH 64
#define ED 512       // expert dim
#define NEXP 10
#define NEXPA 11     // incl. shared expert as #10
#define TOPKE 3
#define NLAYER 4
#define NVOCAB 32000
#define NSLOT (BT * TOPKE)   // 12288 routed slots
#define NSLOTA (NSLOT + BT)  // + 4096 shared slots = 16384
#define NSB 12               // setup blocks (NSLOT / 1024)

typedef __attribute__((ext_vector_type(8))) short bf16x8;
typedef __attribute__((ext_vector_type(4))) short bf16x4;
typedef __attribute__((ext_vector_type(4))) float f32x4;

__device__ __forceinline__ float gelu_f(float x) {
  return 0.5f * x * (1.0f + erff(x * 0.70710678118654752440f));
}

// async global->LDS, 16B per lane, 64 lanes = 1KB per call.
__device__ __forceinline__ void gll16(const void* g, void* l) {
  __builtin_amdgcn_global_load_lds(
      (const __attribute__((address_space(1))) unsigned int*)g,
      (__attribute__((address_space(3))) unsigned int*)l, 16, 0, 0);
}

// counted-vmcnt barrier primitives (T4): leave prefetch loads in flight
#define VMWAIT4() asm volatile("s_waitcnt vmcnt(4)" ::: "memory")
#define VMWAIT3() asm volatile("s_waitcnt vmcnt(3)" ::: "memory")
#define VMWAIT0() asm volatile("s_waitcnt vmcnt(0)" ::: "memory")
#define BAR() __builtin_amdgcn_s_barrier()
#define SCHEDB() __builtin_amdgcn_sched_barrier(0)

// ---------------- embed + LN1(layer0): h = W_emb[x]+W_pos; lno_bf = LN(h) ----
__global__ __launch_bounds__(256) void k_embed_ln(const int* __restrict__ x,
                                                  const float* __restrict__ Wemb,
                                                  const float* __restrict__ Wpos,
                                                  const float* __restrict__ g,
                                                  const float* __restrict__ b,
                                                  float* __restrict__ h,
                                                  __hip_bfloat16* __restrict__ outb) {
  const int t = blockIdx.x;
  const int tid = threadIdx.x;
  const int pos = t & 1023;
  const int tok = x[t];
  float4 a = ((const float4*)(Wemb + (size_t)tok * HD))[tid];
  float4 p = ((const float4*)(Wpos + (size_t)pos * HD))[tid];
  float4 v = make_float4(a.x + p.x, a.y + p.y, a.z + p.z, a.w + p.w);
  ((float4*)(h + (size_t)t * HD))[tid] = v;
  float s = v.x + v.y + v.z + v.w;
  float ss = v.x * v.x + v.y * v.y + v.z * v.z + v.w * v.w;
#pragma unroll
  for (int o = 32; o > 0; o >>= 1) { s += __shfl_down(s, o); ss += __shfl_down(ss, o); }
  __shared__ float rs[4], rss[4];
  if ((tid & 63) == 0) { rs[tid >> 6] = s; rss[tid >> 6] = ss; }
  __syncthreads();
  const float S = rs[0] + rs[1] + rs[2] + rs[3];
  const float SS = rss[0] + rss[1] + rss[2] + rss[3];
  const float mean = S * (1.0f / HD);
  const float inv = rsqrtf(SS * (1.0f / HD) - mean * mean + 1e-5f);
  const float4 gg = ((const float4*)g)[tid];
  const float4 bb = ((const float4*)b)[tid];
  union { bf16x4 v; __hip_bfloat16 e[4]; } u;
  u.e[0] = __float2bfloat16((v.x - mean) * inv * gg.x + bb.x);
  u.e[1] = __float2bfloat16((v.y - mean) * inv * gg.y + bb.y);
  u.e[2] = __float2bfloat16((v.z - mean) * inv * gg.z + bb.z);
  u.e[3] = __float2bfloat16((v.w - mean) * inv * gg.w + bb.w);
  *(bf16x4*)(outb + (size_t)t * HD + tid * 4) = u.v;
}

// ---------------- weight transpose + fp32->bf16: [z][K][N] -> [z'][N][K] -----
__global__ __launch_bounds__(256) void k_wtrans(const float* __restrict__ in,
                                                __hip_bfloat16* __restrict__ out,
                                                int K, int N,
                                                int srcPer, int dstPer, int dstOff) {
  const int z = blockIdx.z;
  const int dz = (z / srcPer) * dstPer + (z % srcPer) + dstOff;
  const float* src = in + (size_t)z * K * N;
  __hip_bfloat16* dst = out + (size_t)dz * N * K;
  __shared__ float t[64][65];
  const int tid = threadIdx.x;
  const int k0 = blockIdx.y * 64, n0 = blockIdx.x * 64;
#pragma unroll
  for (int i = 0; i < 4; ++i) {
    const int r = (tid >> 4) + i * 16;
    const int c = (tid & 15) * 4;
    float4 v = *(const float4*)(src + (size_t)(k0 + r) * N + n0 + c);
    t[r][c] = v.x; t[r][c + 1] = v.y; t[r][c + 2] = v.z; t[r][c + 3] = v.w;
  }
  __syncthreads();
#pragma unroll
  for (int i = 0; i < 2; ++i) {
    const int n = (tid >> 3) + i * 32;
    const int k = (tid & 7) * 8;
    union { bf16x8 v; __hip_bfloat16 e[8]; } u;
#pragma unroll
    for (int j = 0; j < 8; ++j) u.e[j] = __float2bfloat16(t[k + j][n]);
    *(bf16x8*)(dst + (size_t)(n0 + n) * K + k0 + k) = u.v;
  }
}

// ---------------- router weight transpose: Wr [L][HD][NEXP] -> [L][NEXP][HD] --
__global__ __launch_bounds__(256) void k_wrtrans(const float* __restrict__ in,
                                                 float* __restrict__ out) {
  const int l = blockIdx.x;
  const float* src = in + (size_t)l * HD * NEXP;
  float* dst = out + (size_t)l * NEXP * HD;
  for (int idx = threadIdx.x; idx < NEXP * HD; idx += 256) {
    const int e = idx / HD, k = idx - e * HD;
    dst[idx] = src[(size_t)k * NEXP + e];
  }
}

// ---------------- V transpose per (b,h): qkv V part -> vt[(bh*64+d)][1024 t] --
__global__ __launch_bounds__(256) void k_vtrans(const __hip_bfloat16* __restrict__ qkv,
                                                __hip_bfloat16* __restrict__ vt) {
  const int bh = blockIdx.x, tt = blockIdx.y;
  const int b = bh >> 4, h = bh & 15;
  __shared__ __hip_bfloat16 t[64][72];
  for (int c = threadIdx.x; c < 512; c += 256) {
    int r = c >> 3, d0 = (c & 7) * 8;
    *(bf16x8*)&t[r][d0] =
        *(const bf16x8*)(qkv + ((size_t)(b * 1024 + tt * 64 + r)) * 3072 + 2048 + h * 64 + d0);
  }
  __syncthreads();
  for (int c = threadIdx.x; c < 512; c += 256) {
    int d = c >> 3, t0 = (c & 7) * 8;
    union { bf16x8 v; __hip_bfloat16 e[8]; } u;
#pragma unroll
    for (int j = 0; j < 8; ++j) u.e[j] = t[t0 + j][d];
    *(bf16x8*)(vt + ((size_t)(bh * 64 + d)) * 1024 + tt * 64 + t0) = u.v;
  }
}

// ---------------- fused LN2 + router (bf16 input) ----------------
__global__ __launch_bounds__(256) void k_ln_router(const __hip_bfloat16* __restrict__ in,
                                                   const float* __restrict__ g,
                                                   const float* __restrict__ b,
                                                   const float* __restrict__ Wrt,
                                                   __hip_bfloat16* __restrict__ outb,
                                                   float* __restrict__ gates,
                                                   int* __restrict__ eidx) {
  const int row = blockIdx.x;
  const int tid = threadIdx.x;
  __shared__ float xs[HD];
  __shared__ float rs[4], rss[4];
  __shared__ float lg[16];
  union { bf16x4 v; __hip_bfloat16 e[4]; } iv;
  iv.v = *(const bf16x4*)(in + (size_t)row * HD + tid * 4);
  const float4 v = make_float4(__bfloat162float(iv.e[0]), __bfloat162float(iv.e[1]),
                               __bfloat162float(iv.e[2]), __bfloat162float(iv.e[3]));
  float s = v.x + v.y + v.z + v.w;
  float ss = v.x * v.x + v.y * v.y + v.z * v.z + v.w * v.w;
#pragma unroll
  for (int o = 32; o > 0; o >>= 1) { s += __shfl_down(s, o); ss += __shfl_down(ss, o); }
  if ((tid & 63) == 0) { rs[tid >> 6] = s; rss[tid >> 6] = ss; }
  __syncthreads();
  const float S = rs[0] + rs[1] + rs[2] + rs[3];
  const float SS = rss[0] + rss[1] + rss[2] + rss[3];
  const float mean = S * (1.0f / HD);
  const float inv = rsqrtf(SS * (1.0f / HD) - mean * mean + 1e-5f);
  const float4 gg = ((const float4*)g)[tid];
  const float4 bb = ((const float4*)b)[tid];
  const float o0 = (v.x - mean) * inv * gg.x + bb.x;
  const float o1 = (v.y - mean) * inv * gg.y + bb.y;
  const float o2 = (v.z - mean) * inv * gg.z + bb.z;
  const float o3 = (v.w - mean) * inv * gg.w + bb.w;
  union { bf16x4 v; __hip_bfloat16 e[4]; } u;
  u.e[0] = __float2bfloat16(o0); u.e[1] = __float2bfloat16(o1);
  u.e[2] = __float2bfloat16(o2); u.e[3] = __float2bfloat16(o3);
  *(bf16x4*)(outb + (size_t)row * HD + tid * 4) = u.v;
  ((float4*)xs)[tid] = make_float4(o0, o1, o2, o3);
  __syncthreads();
  const int wv = tid >> 6, lane = tid & 63;
  for (int e = wv; e < NEXP; e += 4) {
    const float4* wr4 = (const float4*)(Wrt + (size_t)e * HD);
    float d = 0.f;
#pragma unroll
    for (int i = 0; i < 4; ++i) {
      float4 xv = ((const float4*)xs)[lane + i * 64];
      float4 wv4 = wr4[lane + i * 64];
      d += xv.x * wv4.x + xv.y * wv4.y + xv.z * wv4.z + xv.w * wv4.w;
    }
#pragma unroll
    for (int o = 32; o > 0; o >>= 1) d += __shfl_down(d, o);
    if (lane == 0) lg[e] = d;
  }
  __syncthreads();
  if (tid == 0) {
    float m = lg[0];
#pragma unroll
    for (int e = 1; e < NEXP; ++e) m = fmaxf(m, lg[e]);
    float p[NEXP], sum = 0.f;
#pragma unroll
    for (int e = 0; e < NEXP; ++e) { p[e] = __expf(lg[e] - m); sum += p[e]; }
    const float isum = 1.0f / sum;
#pragma unroll
    for (int e = 0; e < NEXP; ++e) p[e] *= isum;
    bool used[NEXP] = {};
    for (int k = 0; k < TOPKE; ++k) {
      int best = -1; float bv = -1.f;
      for (int e = 0; e < NEXP; ++e)
        if (!used[e] && p[e] > bv) { bv = p[e]; best = e; }
      used[best] = true;
      eidx[row * TOPKE + k] = best;
      gates[row * TOPKE + k] = bv;
    }
  }
}

// final LN over the 4 last-token rows only
__global__ __launch_bounds__(256) void k_lnf(const float* __restrict__ h,
                                             const float* __restrict__ g,
                                             const float* __restrict__ b,
                                             float* __restrict__ hf) {
  const int row = blockIdx.x * 1024 + 1023;
  const int tid = threadIdx.x;
  const float* xr = h + (size_t)row * HD;
  float s = 0.f, ss = 0.f;
  for (int i = tid; i < HD; i += 256) { float v = xr[i]; s += v; ss += v * v; }
#pragma unroll
  for (int o = 32; o > 0; o >>= 1) { s += __shfl_down(s, o); ss += __shfl_down(ss, o); }
  __shared__ float rs[4], rss[4];
  if ((tid & 63) == 0) { rs[tid >> 6] = s; rss[tid >> 6] = ss; }
  __syncthreads();
  const float S = rs[0] + rs[1] + rs[2] + rs[3];
  const float SS = rss[0] + rss[1] + rss[2] + rss[3];
  const float mean = S * (1.0f / HD);
  const float inv = rsqrtf(SS * (1.0f / HD) - mean * mean + 1e-5f);
  float* orow = hf + (size_t)blockIdx.x * HD;
  for (int i = tid; i < HD; i += 256) {
    float v = xr[i];
    orow[i] = (v - mean) * inv * g[i] + b[i];
  }
}

// ---- 128-wide tile staging/compute (QKV GEMM) ----
#define STAGE_AB(dA, dB, kk)                                  \
  do {                                                        \
    gll16(ga + (kk), &dA[(w * 32) * 32]);                     \
    gll16(ga + (size_t)16 * K + (kk), &dA[(w * 32 + 16) * 32]); \
    gll16(gb + (kk), &dB[(w * 32) * 32]);                     \
    gll16(gb + (size_t)16 * K + (kk), &dB[(w * 32 + 16) * 32]); \
  } while (0)

#define COMPUTE_AB(sA, sB)                                                        \
  do {                                                                            \
    bf16x8 af[4], bfv[4];                                                         \
    _Pragma("unroll") for (int m = 0; m < 4; ++m) af[m] = *(const bf16x8*)&sA[aidx[m]]; \
    _Pragma("unroll") for (int n = 0; n < 4; ++n) bfv[n] = *(const bf16x8*)&sB[bidx[n]]; \
    _Pragma("unroll") for (int m = 0; m < 4; ++m)                                 \
      _Pragma("unroll") for (int n = 0; n < 4; ++n)                               \
        acc[m][n] = __builtin_amdgcn_mfma_f32_16x16x32_bf16(af[m], bfv[n], acc[m][n], 0, 0, 0); \
  } while (0)

#define KLOOP(STAGER, VMW)                                     \
  do {                                                         \
    STAGER(As0, Bs0, 0);                                       \
    for (int k0 = 0; k0 < K; k0 += 64) {                       \
      STAGER(As1, Bs1, k0 + 32);                               \
      VMW(); BAR(); SCHEDB();                                  \
      COMPUTE_AB(As0, Bs0);                                    \
      BAR();                                                   \
      if (k0 + 64 < K) { STAGER(As0, Bs0, k0 + 64); VMW(); }   \
      else VMWAIT0();                                          \
      BAR(); SCHEDB();                                         \
      COMPUTE_AB(As1, Bs1);                                    \
      BAR();                                                   \
    }                                                          \
  } while (0)

// ---- 64-wide-N tile staging/compute (Wo + MoE GEMMs): 128Mx64N, 3 loads/wave --
#define STAGE64_AB(dA, dB, kk)                                \
  do {                                                        \
    gll16(ga + (kk), &dA[(w * 32) * 32]);                     \
    gll16(ga + (size_t)16 * K + (kk), &dA[(w * 32 + 16) * 32]); \
    gll16(gbn + (kk), &dB[(w * 16) * 32]);                    \
  } while (0)

#define STAGE64_AB2(dA, dB, kk)                               \
  do {                                                        \
    gll16(ga0 + (kk), &dA[(w * 32) * 32]);                    \
    gll16(ga1 + (kk), &dA[(w * 32 + 16) * 32]);               \
    gll16(gbn + (kk), &dB[(w * 16) * 32]);                    \
  } while (0)

#define COMPUTE64(sA, sB)                                                         \
  do {                                                                            \
    bf16x8 af[4], bfv[2];                                                         \
    _Pragma("unroll") for (int m = 0; m < 4; ++m) af[m] = *(const bf16x8*)&sA[aidx[m]]; \
    _Pragma("unroll") for (int n = 0; n < 2; ++n) bfv[n] = *(const bf16x8*)&sB[bidx[n]]; \
    _Pragma("unroll") for (int m = 0; m < 4; ++m)                                 \
      _Pragma("unroll") for (int n = 0; n < 2; ++n)                               \
        acc[m][n] = __builtin_amdgcn_mfma_f32_16x16x32_bf16(af[m], bfv[n], acc[m][n], 0, 0, 0); \
  } while (0)

#define KLOOP64(STAGER)                                        \
  do {                                                         \
    STAGER(As0, Bs0, 0);                                       \
    for (int k0 = 0; k0 < K; k0 += 64) {                       \
      STAGER(As1, Bs1, k0 + 32);                               \
      VMWAIT3(); BAR(); SCHEDB();                              \
      COMPUTE64(As0, Bs0);                                     \
      BAR();                                                   \
      if (k0 + 64 < K) { STAGER(As0, Bs0, k0 + 64); VMWAIT3(); } \
      else VMWAIT0();                                          \
      BAR(); SCHEDB();                                         \
      COMPUTE64(As1, Bs1);                                     \
      BAR();                                                   \
    }                                                          \
  } while (0)

// ---------------- bf16 MFMA GEMM (128x128): C = A @ Bt^T ----------------
// EPI: 0 none, 2 +residual R.  OBF: 1 -> bf16 out, 0 -> fp32 out.
template <int EPI, int OBF>
__global__ __launch_bounds__(256) void k_mgemm(const __hip_bfloat16* __restrict__ A,
                                               const __hip_bfloat16* __restrict__ Bt,
                                               const float* __restrict__ R,
                                               float* __restrict__ C,
                                               __hip_bfloat16* __restrict__ Cb,
                                               int M, int N, int K) {
  __shared__ __hip_bfloat16 As0[128 * 32];
  __shared__ __hip_bfloat16 Bs0[128 * 32];
  __shared__ __hip_bfloat16 As1[128 * 32];
  __shared__ __hip_bfloat16 Bs1[128 * 32];
  const int tid = threadIdx.x;
  const int w = tid >> 6, lane = tid & 63;
  const int wr = w >> 1, wc = w & 1;
  const int m0 = blockIdx.y << 7, n0 = blockIdx.x << 7;
  const int srow = lane >> 2;
  const int scol = (lane & 3) * 8;
  const int kq = (lane >> 4) * 8;
  int aidx[4], bidx[4];
#pragma unroll
  for (int m = 0; m < 4; ++m) aidx[m] = (wr * 64 + m * 16 + (lane & 15)) * 32 + kq;
#pragma unroll
  for (int n = 0; n < 4; ++n) bidx[n] = (wc * 64 + n * 16 + (lane & 15)) * 32 + kq;

  f32x4 acc[4][4];
#pragma unroll
  for (int m = 0; m < 4; ++m)
#pragma unroll
    for (int n = 0; n < 4; ++n) acc[m][n] = (f32x4){0.f, 0.f, 0.f, 0.f};

  const __hip_bfloat16* ga = A + (size_t)(m0 + w * 32 + srow) * K + scol;
  const __hip_bfloat16* gb = Bt + (size_t)(n0 + w * 32 + srow) * K + scol;

  KLOOP(STAGE_AB, VMWAIT4);

#pragma unroll
  for (int m = 0; m < 4; ++m) {
#pragma unroll
    for (int n = 0; n < 4; ++n) {
#pragma unroll
      for (int r = 0; r < 4; ++r) {
        const int row = m0 + wr * 64 + m * 16 + (lane >> 4) * 4 + r;
        const int col = n0 + wc * 64 + n * 16 + (lane & 15);
        float v = acc[m][n][r];
        if (EPI == 2) v += R[(size_t)row * N + col];
        if (OBF) Cb[(size_t)row * N + col] = __float2bfloat16(v);
        else C[(size_t)row * N + col] = v;
      }
    }
  }
}

// ---------------- bf16 MFMA GEMM (128Mx64N): higher occupancy ----------------
template <int EPI, int OBF>
__global__ __launch_bounds__(256) void k_mgemm64(const __hip_bfloat16* __restrict__ A,
                                                 const __hip_bfloat16* __restrict__ Bt,
                                                 const float* __restrict__ R,
                                                 float* __restrict__ C,
                                                 __hip_bfloat16* __restrict__ Cb,
                                                 int M, int N, int K) {
  __shared__ __hip_bfloat16 As0[128 * 32];
  __shared__ __hip_bfloat16 Bs0[64 * 32];
  __shared__ __hip_bfloat16 As1[128 * 32];
  __shared__ __hip_bfloat16 Bs1[64 * 32];
  const int tid = threadIdx.x;
  const int w = tid >> 6, lane = tid & 63;
  const int wr = w & 1, wc = w >> 1;
  const int m0 = blockIdx.y << 7, n0 = blockIdx.x << 6;
  const int srow = lane >> 2;
  const int scol = (lane & 3) * 8;
  const int kq = (lane >> 4) * 8;
  int aidx[4], bidx[2];
#pragma unroll
  for (int m = 0; m < 4; ++m) aidx[m] = (wr * 64 + m * 16 + (lane & 15)) * 32 + kq;
#pragma unroll
  for (int n = 0; n < 2; ++n) bidx[n] = (wc * 32 + n * 16 + (lane & 15)) * 32 + kq;

  f32x4 acc[4][2];
#pragma unroll
  for (int m = 0; m < 4; ++m)
#pragma unroll
    for (int n = 0; n < 2; ++n) acc[m][n] = (f32x4){0.f, 0.f, 0.f, 0.f};

  const __hip_bfloat16* ga = A + (size_t)(m0 + w * 32 + srow) * K + scol;
  const __hip_bfloat16* gbn = Bt + (size_t)(n0 + w * 16 + srow) * K + scol;

  KLOOP64(STAGE64_AB);

#pragma unroll
  for (int m = 0; m < 4; ++m) {
#pragma unroll
    for (int n = 0; n < 2; ++n) {
#pragma unroll
      for (int r = 0; r < 4; ++r) {
        const int row = m0 + wr * 64 + m * 16 + (lane >> 4) * 4 + r;
        const int col = n0 + wc * 32 + n * 16 + (lane & 15);
        float v = acc[m][n][r];
        if (EPI == 2) v += R[(size_t)row * N + col];
        if (OBF) Cb[(size_t)row * N + col] = __float2bfloat16(v);
        else C[(size_t)row * N + col] = v;
      }
    }
  }
}

// ---------------- grouped MoE GEMM (128Mx64N) over 11 experts ----------------
// EPI: 1 = gelu (up), 3 = gate-scale (down). Tile derived from counts scan.
template <int EPI>
__global__ __launch_bounds__(256) void k_mgemm_moe64(const __hip_bfloat16* __restrict__ A,
                                                     const __hip_bfloat16* __restrict__ Btbase,
                                                     __hip_bfloat16* __restrict__ Cb,
                                                     const int* __restrict__ counts,
                                                     const int* __restrict__ offs,
                                                     const int* __restrict__ row_slot,
                                                     const float* __restrict__ gate_slot,
                                                     int N, int K, int gather) {
  int T = blockIdx.y;
  int e = -1, r0 = 0, acc0 = 0;
#pragma unroll
  for (int ee = 0; ee < NEXPA; ++ee) {
    const int nt = (counts[ee] + 127) >> 7;
    if (e < 0 && T < acc0 + nt) { e = ee; r0 = (T - acc0) << 7; }
    acc0 += nt;
  }
  if (e < 0) return;
  const int cnt = counts[e], off = offs[e];
  const __hip_bfloat16* Bt = Btbase + (size_t)e * N * K;

  __shared__ __hip_bfloat16 As0[128 * 32];
  __shared__ __hip_bfloat16 Bs0[64 * 32];
  __shared__ __hip_bfloat16 As1[128 * 32];
  __shared__ __hip_bfloat16 Bs1[64 * 32];
  const int tid = threadIdx.x;
  const int w = tid >> 6, lane = tid & 63;
  const int wr = w & 1, wc = w >> 1;
  const int n0 = blockIdx.x << 6;
  const int srow = lane >> 2;
  const int scol = (lane & 3) * 8;
  const int kq = (lane >> 4) * 8;
  int aidx[4], bidx[2];
#pragma unroll
  for (int m = 0; m < 4; ++m) aidx[m] = (wr * 64 + m * 16 + (lane & 15)) * 32 + kq;
#pragma unroll
  for (int n = 0; n < 2; ++n) bidx[n] = (wc * 32 + n * 16 + (lane & 15)) * 32 + kq;

  const int last = off + cnt - 1;
  int s0 = off + r0 + w * 32 + srow;        if (s0 > last) s0 = last;
  int s1 = off + r0 + w * 32 + 16 + srow;   if (s1 > last) s1 = last;
  const int arow0 = gather ? row_slot[s0] : s0;
  const int arow1 = gather ? row_slot[s1] : s1;

  f32x4 acc[4][2];
#pragma unroll
  for (int m = 0; m < 4; ++m)
#pragma unroll
    for (int n = 0; n < 2; ++n) acc[m][n] = (f32x4){0.f, 0.f, 0.f, 0.f};

  const __hip_bfloat16* ga0 = A + (size_t)arow0 * K + scol;
  const __hip_bfloat16* ga1 = A + (size_t)arow1 * K + scol;
  const __hip_bfloat16* gbn = Bt + (size_t)(n0 + w * 16 + srow) * K + scol;

  KLOOP64(STAGE64_AB2);

#pragma unroll
  for (int m = 0; m < 4; ++m) {
#pragma unroll
    for (int r = 0; r < 4; ++r) {
      const int rl = wr * 64 + m * 16 + (lane >> 4) * 4 + r;
      if (r0 + rl < cnt) {
        const int slot = off + r0 + rl;
        const float sc = (EPI == 3) ? gate_slot[slot] : 1.0f;
#pragma unroll
        for (int n = 0; n < 2; ++n) {
          const int col = n0 + wc * 32 + n * 16 + (lane & 15);
          float v = acc[m][n][r];
          if (EPI == 1) v = gelu_f(v);
          else v *= sc;
          Cb[(size_t)slot * N + col] = __float2bfloat16(v);
        }
      }
    }
  }
}

// ---------------- MFMA flash attention (swapped QK^T), 128 q rows / block -----
// T14 async-STAGE split: next K/V tile loaded to regs before compute,
// written to LDS after the compute barrier. T5 setprio around MFMA clusters.
__global__ __launch_bounds__(256) void k_mattn(const __hip_bfloat16* __restrict__ qkv,
                                               const __hip_bfloat16* __restrict__ vt,
                                               __hip_bfloat16* __restrict__ y) {
  const int bh = blockIdx.x;
  const int qt = 7 - (int)blockIdx.y;          // big causal blocks first
  const int b = bh >> 4, hh = bh & 15;
  const int tid = threadIdx.x;
  const int w = tid >> 6, lane = tid & 63;
  const int l15 = lane & 15, g = lane >> 4;
  const int swl = (l15 & 7) << 3;

  __shared__ __hip_bfloat16 Ks[64 * 64];
  __shared__ __hip_bfloat16 Vs[64 * 64];
  __shared__ __hip_bfloat16 Pw[2][4][16 * 64];

  // staging coordinates: chunk i covers row i*32+(tid>>3), col (tid&7)*8
  const int srow = tid >> 3;             // 0..31
  const int scc = (tid & 7) * 8;
  const int ssw = scc ^ ((srow & 7) << 3);
  bf16x8 kreg[2], vreg[2];

#define LOADT(kt)                                                                  \
  do {                                                                             \
    _Pragma("unroll") for (int i = 0; i < 2; ++i) {                                \
      const int r = i * 32 + srow;                                                 \
      kreg[i] = *(const bf16x8*)(qkv +                                             \
          ((size_t)(b * 1024 + (kt) * 64 + r)) * 3072 + 1024 + hh * 64 + scc);     \
      vreg[i] = *(const bf16x8*)(vt +                                              \
          ((size_t)(bh * 64 + r)) * 1024 + (kt) * 64 + scc);                       \
    }                                                                              \
  } while (0)

#define WRITET()                                                                   \
  do {                                                                             \
    _Pragma("unroll") for (int i = 0; i < 2; ++i) {                                \
      const int r = i * 32 + srow;                                                 \
      *(bf16x8*)&Ks[r * 64 + ssw] = kreg[i];                                       \
      *(bf16x8*)&Vs[r * 64 + ssw] = vreg[i];                                       \
    }                                                                              \
  } while (0)

  bf16x8 qf[2][2];
#pragma unroll
  for (int s = 0; s < 2; ++s) {
    const __hip_bfloat16* qp =
        qkv + ((size_t)(b * 1024 + qt * 128 + s * 64 + w * 16 + l15)) * 3072 + hh * 64 + g * 8;
    qf[s][0] = *(const bf16x8*)qp;
    qf[s][1] = *(const bf16x8*)(qp + 32);
  }

  f32x4 yacc[2][4];
#pragma unroll
  for (int s = 0; s < 2; ++s)
#pragma unroll
    for (int nt = 0; nt < 4; ++nt) yacc[s][nt] = (f32x4){0.f, 0.f, 0.f, 0.f};
  float m_s[2] = {-INFINITY, -INFINITY};
  float l_s[2] = {0.f, 0.f};
  const int qg0 = qt * 128 + w * 16 + l15;

  const int ktmax = 2 * qt + 1;
  // prologue: tile 0 into LDS
  LOADT(0);
  WRITET();
  __syncthreads();

  for (int kt = 0; kt <= ktmax; ++kt) {
    // issue next tile's global loads early; latency hides under compute
    if (kt < ktmax) LOADT(kt + 1);

    bf16x8 kf[4][2];
#pragma unroll
    for (int m = 0; m < 4; ++m) {
      const int row = m * 16 + l15;
#pragma unroll
      for (int kk = 0; kk < 2; ++kk)
        kf[m][kk] = *(const bf16x8*)&Ks[row * 64 + ((kk * 32 + g * 8) ^ swl)];
    }
    bf16x8 pa[2][2] = {};
#pragma unroll
    for (int s = 0; s < 2; ++s) {
      if (kt > 2 * qt + s) continue;
      f32x4 st[4];
#pragma unroll
      for (int m = 0; m < 4; ++m) st[m] = (f32x4){0.f, 0.f, 0.f, 0.f};
      __builtin_amdgcn_s_setprio(1);
#pragma unroll
      for (int m = 0; m < 4; ++m)
#pragma unroll
        for (int kk = 0; kk < 2; ++kk)
          st[m] = __builtin_amdgcn_mfma_f32_16x16x32_bf16(kf[m][kk], qf[s][kk], st[m], 0, 0, 0);
      __builtin_amdgcn_s_setprio(0);
      const int qg = qg0 + s * 64;
      const bool dia = (kt == 2 * qt + s);
      float tmax = -INFINITY;
#pragma unroll
      for (int m = 0; m < 4; ++m)
#pragma unroll
        for (int r = 0; r < 4; ++r) {
          float v = st[m][r] * 0.125f;
          if (dia && (kt * 64 + m * 16 + g * 4 + r) > qg) v = -INFINITY;
          st[m][r] = v;
          tmax = fmaxf(tmax, v);
        }
      tmax = fmaxf(tmax, __shfl_xor(tmax, 16));
      tmax = fmaxf(tmax, __shfl_xor(tmax, 32));
      const float mnew = fmaxf(m_s[s], tmax);
      const float fac = __expf(m_s[s] - mnew);
      m_s[s] = mnew;
      float tsum = 0.f;
#pragma unroll
      for (int m = 0; m < 4; ++m)
#pragma unroll
        for (int r = 0; r < 4; ++r) {
          float p = __expf(st[m][r] - mnew);
          st[m][r] = p;
          tsum += p;
        }
      tsum += __shfl_xor(tsum, 16);
      tsum += __shfl_xor(tsum, 32);
      l_s[s] = l_s[s] * fac + tsum;
      float fq[4];
#pragma unroll
      for (int r = 0; r < 4; ++r) fq[r] = __shfl(fac, g * 4 + r);
#pragma unroll
      for (int nt = 0; nt < 4; ++nt)
#pragma unroll
        for (int r = 0; r < 4; ++r) yacc[s][nt][r] *= fq[r];
#pragma unroll
      for (int m = 0; m < 4; ++m) {
        union { bf16x4 v; __hip_bfloat16 e[4]; } pk;
#pragma unroll
        for (int r = 0; r < 4; ++r) pk.e[r] = __float2bfloat16(st[m][r]);
        *(bf16x4*)&Pw[s][w][l15 * 64 + ((m * 16 + g * 4) ^ swl)] = pk.v;
      }
#pragma unroll
      for (int kk = 0; kk < 2; ++kk)
        pa[s][kk] = *(const bf16x8*)&Pw[s][w][l15 * 64 + ((kk * 32 + g * 8) ^ swl)];
    }
    const bool v0 = (kt <= 2 * qt);
    __builtin_amdgcn_s_setprio(1);
#pragma unroll
    for (int kk = 0; kk < 2; ++kk)
#pragma unroll
      for (int nt = 0; nt < 4; ++nt) {
        bf16x8 vf = *(const bf16x8*)&Vs[(nt * 16 + l15) * 64 + ((kk * 32 + g * 8) ^ swl)];
        if (v0) yacc[0][nt] = __builtin_amdgcn_mfma_f32_16x16x32_bf16(pa[0][kk], vf, yacc[0][nt], 0, 0, 0);
        yacc[1][nt] = __builtin_amdgcn_mfma_f32_16x16x32_bf16(pa[1][kk], vf, yacc[1][nt], 0, 0, 0);
      }
    __builtin_amdgcn_s_setprio(0);

    if (kt < ktmax) {
      __syncthreads();   // all waves done reading Ks/Vs (and Pw)
      WRITET();          // implicit vmcnt wait lands here, after compute
      __syncthreads();   // next tile visible
    }
  }
#pragma unroll
  for (int s = 0; s < 2; ++s) {
    const float inv = 1.0f / l_s[s];
    float iq[4];
#pragma unroll
    for (int r = 0; r < 4; ++r) iq[r] = __shfl(inv, g * 4 + r);
#pragma unroll
    for (int r = 0; r < 4; ++r) {
      __hip_bfloat16* yp =
          y + ((size_t)(b * 1024 + qt * 128 + s * 64 + w * 16 + g * 4 + r)) * HD + hh * 64 + l15;
#pragma unroll
      for (int nt = 0; nt < 4; ++nt)
        yp[nt * 16] = __float2bfloat16(yacc[s][nt][r] * iq[r]);
    }
  }
#undef LOADT
#undef WRITET
}

// ---------------- MoE setup: per-block hist, then prefix+scatter ----------------
__global__ __launch_bounds__(1024) void k_hist(const int* __restrict__ eidx,
                                               int* __restrict__ hist_g) {
  __shared__ int lh[16];
  const int tid = threadIdx.x;
  if (tid < 16) lh[tid] = 0;
  __syncthreads();
  atomicAdd(&lh[eidx[blockIdx.x * 1024 + tid]], 1);
  __syncthreads();
  if (tid < 16) hist_g[blockIdx.x * 16 + tid] = lh[tid];
}

__global__ __launch_bounds__(1024) void k_scatter2(const int* __restrict__ eidx,
                                                   const float* __restrict__ gates,
                                                   const int* __restrict__ hist_g,
                                                   int* __restrict__ counts,
                                                   int* __restrict__ offs,
                                                   int* __restrict__ row_slot,
                                                   float* __restrict__ gate_slot,
                                                   int* __restrict__ slot_of) {
  __shared__ int lcur[16];
  const int tid = threadIdx.x;
  const int blk = blockIdx.x;
  if (tid == 0) {
    int off = 0;
    for (int e = 0; e < NEXP; ++e) {
      int pre = 0, tot = 0;
      for (int b = 0; b < NSB; ++b) {
        const int hc = hist_g[b * 16 + e];
        if (b < blk) pre += hc;
        tot += hc;
      }
      lcur[e] = off + pre;
      if (blk == 0) { counts[e] = tot; offs[e] = off; }
      off += tot;
    }
    if (blk == 0) { counts[NEXP] = BT; offs[NEXP] = NSLOT; }
  }
  __syncthreads();
  const int i = blk * 1024 + tid;
  const int e = eidx[i];
  const int pos = atomicAdd(&lcur[e], 1);
  row_slot[pos] = i / TOPKE;
  gate_slot[pos] = gates[i];
  slot_of[i] = pos;
  if (i < BT) { row_slot[NSLOT + i] = i; gate_slot[NSLOT + i] = 1.0f; }
}

// ---------------- combine (+ next-layer LN1): h += 3 routed + shared ----------
template <int DOLN>
__global__ __launch_bounds__(256) void k_combine_ln(float* __restrict__ h,
                                                    const __hip_bfloat16* __restrict__ rd,
                                                    const int* __restrict__ slot_of,
                                                    const float* __restrict__ g,
                                                    const float* __restrict__ b,
                                                    __hip_bfloat16* __restrict__ outb) {
  const int t = blockIdx.x;
  const int tid = threadIdx.x;
  const int s0 = slot_of[t * 3 + 0], s1 = slot_of[t * 3 + 1], s2 = slot_of[t * 3 + 2];
  const int s3 = NSLOT + t;
  float4 hv = ((float4*)(h + (size_t)t * HD))[tid];
  union { bf16x4 v; __hip_bfloat16 e[4]; } r0, r1, r2, r3;
  r0.v = *(const bf16x4*)(rd + (size_t)s0 * HD + tid * 4);
  r1.v = *(const bf16x4*)(rd + (size_t)s1 * HD + tid * 4);
  r2.v = *(const bf16x4*)(rd + (size_t)s2 * HD + tid * 4);
  r3.v = *(const bf16x4*)(rd + (size_t)s3 * HD + tid * 4);
  hv.x += __bfloat162float(r0.e[0]) + __bfloat162float(r1.e[0]) + __bfloat162float(r2.e[0]) + __bfloat162float(r3.e[0]);
  hv.y += __bfloat162float(r0.e[1]) + __bfloat162float(r1.e[1]) + __bfloat162float(r2.e[1]) + __bfloat162float(r3.e[1]);
  hv.z += __bfloat162float(r0.e[2]) + __bfloat162float(r1.e[2]) + __bfloat162float(r2.e[2]) + __bfloat162float(r3.e[2]);
  hv.w += __bfloat162float(r0.e[3]) + __bfloat162float(r1.e[3]) + __bfloat162float(r2.e[3]) + __bfloat162float(r3.e[3]);
  ((float4*)(h + (size_t)t * HD))[tid] = hv;
  if (DOLN) {
    float s = hv.x + hv.y + hv.z + hv.w;
    float ss = hv.x * hv.x + hv.y * hv.y + hv.z * hv.z + hv.w * hv.w;
#pragma unroll
    for (int o = 32; o > 0; o >>= 1) { s += __shfl_down(s, o); ss += __shfl_down(ss, o); }
    __shared__ float rs[4], rss[4];
    if ((tid & 63) == 0) { rs[tid >> 6] = s; rss[tid >> 6] = ss; }
    __syncthreads();
    const float S = rs[0] + rs[1] + rs[2] + rs[3];
    const float SS = rss[0] + rss[1] + rss[2] + rss[3];
    const float mean = S * (1.0f / HD);
    const float inv = rsqrtf(SS * (1.0f / HD) - mean * mean + 1e-5f);
    const float4 gg = ((const float4*)g)[tid];
    const float4 bb = ((const float4*)b)[tid];
    union { bf16x4 v; __hip_bfloat16 e[4]; } u;
    u.e[0] = __float2bfloat16((hv.x - mean) * inv * gg.x + bb.x);
    u.e[1] = __float2bfloat16((hv.y - mean) * inv * gg.y + bb.y);
    u.e[2] = __float2bfloat16((hv.z - mean) * inv * gg.z + bb.z);
    u.e[3] = __float2bfloat16((hv.w - mean) * inv * gg.w + bb.w);
    *(bf16x4*)(outb + (size_t)t * HD + tid * 4) = u.v;
  }
}

// ---------------- tied head: logits[b][v] = dot(hf[b], Wemb[v]) ----------------
__global__ __launch_bounds__(256) void k_head(const float* __restrict__ hf,
                                              const float* __restrict__ Wemb,
                                              float* __restrict__ out) {
  __shared__ float hs[4][HD];
  const int tid = threadIdx.x;
  for (int i = tid; i < HD; i += 256) {
    hs[0][i] = hf[i]; hs[1][i] = hf[HD + i];
    hs[2][i] = hf[2 * HD + i]; hs[3][i] = hf[3 * HD + i];
  }
  __syncthreads();
  const int w = tid >> 6, lane = tid & 63;
  for (int i = 0; i < 4; ++i) {
    const int v = blockIdx.x * 16 + w * 4 + i;
    const float4* wr = (const float4*)(Wemb + (size_t)v * HD);
    float a0 = 0.f, a1 = 0.f, a2 = 0.f, a3 = 0.f;
    for (int q = lane; q < HD / 4; q += 64) {
      float4 wv = wr[q];
      const int k = q * 4;
      a0 += wv.x * hs[0][k] + wv.y * hs[0][k + 1] + wv.z * hs[0][k + 2] + wv.w * hs[0][k + 3];
      a1 += wv.x * hs[1][k] + wv.y * hs[1][k + 1] + wv.z * hs[1][k + 2] + wv.w * hs[1][k + 3];
      a2 += wv.x * hs[2][k] + wv.y * hs[2][k + 1] + wv.z * hs[2][k + 2] + wv.w * hs[2][k + 3];
      a3 += wv.x * hs[3][k] + wv.y * hs[3][k + 1] + wv.z * hs[3][k + 2] + wv.w * hs[3][k + 3];
    }
#pragma unroll
    for (int o = 32; o > 0; o >>= 1) {
      a0 += __shfl_down(a0, o); a1 += __shfl_down(a1, o);
      a2 += __shfl_down(a2, o); a3 += __shfl_down(a3, o);
    }
    if (lane == 0) {
      out[v] = a0; out[NVOCAB + v] = a1;
      out[2 * NVOCAB + v] = a2; out[3 * NVOCAB + v] = a3;
    }
  }
}

extern "C" void kernel_launch(void* const* d_in, const int* in_sizes, int n_in,
                              void* d_out, int out_size, void* d_ws, size_t ws_size,
                              hipStream_t stream) {
  (void)in_sizes; (void)n_in; (void)out_size; (void)ws_size;
  const int* x = (const int*)d_in[0];
  const float* W_emb = (const float*)d_in[1];
  const float* W_pos = (const float*)d_in[2];
  const float* ln1_g = (const float*)d_in[3];
  const float* ln1_b = (const float*)d_in[4];
  const float* Wqkv = (const float*)d_in[5];
  const float* Wo = (const float*)d_in[6];
  const float* ln2_g = (const float*)d_in[7];
  const float* ln2_b = (const float*)d_in[8];
  const float* Wr = (const float*)d_in[9];
  const float* Wsu = (const float*)d_in[10];
  const float* Wsd = (const float*)d_in[11];
  const float* Wu = (const float*)d_in[12];
  const float* Wd = (const float*)d_in[13];
  const float* lnf_g = (const float*)d_in[14];
  const float* lnf_b = (const float*)d_in[15];
  float* out = (float*)d_out;

  float* wsf = (float*)d_ws;
  size_t o = 0;
  float* hbuf = wsf + o; o += (size_t)BT * HD;
  float* hf = wsf + o; o += 4 * HD;
  float* gates = wsf + o; o += NSLOT;
  float* gate_slot = wsf + o; o += NSLOTA;
  int* eidx = (int*)(wsf + o); o += NSLOT;
  int* row_slot = (int*)(wsf + o); o += NSLOTA;
  int* slot_of = (int*)(wsf + o); o += NSLOT;
  int* counts = (int*)(wsf + o); o += 16;
  int* offs = (int*)(wsf + o); o += 16;
  int* hist_g = (int*)(wsf + o); o += NSB * 16;
  float* wr_t = wsf + o; o += (size_t)NLAYER * NEXP * HD;
  // bf16 regions (2 bf16 per float slot)
  __hip_bfloat16* ab_bf  = (__hip_bfloat16*)(wsf + o); o += (size_t)BT * HD / 2;
  __hip_bfloat16* lno_bf = (__hip_bfloat16*)(wsf + o); o += (size_t)BT * HD / 2;
  __hip_bfloat16* ybf    = (__hip_bfloat16*)(wsf + o); o += (size_t)BT * HD / 2;
  __hip_bfloat16* rup_bf = (__hip_bfloat16*)(wsf + o); o += (size_t)NSLOTA * ED / 2;
  // qkv/vt region; later reused as rd_bf
  float* qkvreg = wsf + o; o += (size_t)BT * 3 * HD + (size_t)BT * HD / 2;
  __hip_bfloat16* wqkv_t = (__hip_bfloat16*)(wsf + o); o += (size_t)NLAYER * HD * 3 * HD / 2;
  __hip_bfloat16* wo_t   = (__hip_bfloat16*)(wsf + o); o += (size_t)NLAYER * HD * HD / 2;
  __hip_bfloat16* wu_t   = (__hip_bfloat16*)(wsf + o); o += (size_t)NLAYER * NEXPA * HD * ED / 2;
  __hip_bfloat16* wd_t   = (__hip_bfloat16*)(wsf + o); o += (size_t)NLAYER * NEXPA * ED * HD / 2;
  __hip_bfloat16* qkv_bf = (__hip_bfloat16*)qkvreg;     // BT*3HD bf16
  __hip_bfloat16* vtb = qkv_bf + (size_t)BT * 3 * HD;   // BT*HD bf16
  __hip_bfloat16* rd_bf = (__hip_bfloat16*)qkvreg;      // NSLOTA*HD bf16, after attn

  // weight transpose+convert: [z][K][N] fp32 -> [z'][N][K] bf16
  k_wtrans<<<dim3(3 * HD / 64, HD / 64, NLAYER), 256, 0, stream>>>(
      Wqkv, wqkv_t, HD, 3 * HD, 1, 1, 0);
  k_wtrans<<<dim3(HD / 64, HD / 64, NLAYER), 256, 0, stream>>>(
      Wo, wo_t, HD, HD, 1, 1, 0);
  k_wtrans<<<dim3(ED / 64, HD / 64, NLAYER * NEXP), 256, 0, stream>>>(
      Wu, wu_t, HD, ED, NEXP, NEXPA, 0);
  k_wtrans<<<dim3(ED / 64, HD / 64, NLAYER), 256, 0, stream>>>(
      Wsu, wu_t, HD, ED, 1, NEXPA, NEXP);
  k_wtrans<<<dim3(HD / 64, ED / 64, NLAYER * NEXP), 256, 0, stream>>>(
      Wd, wd_t, ED, HD, NEXP, NEXPA, 0);
  k_wtrans<<<dim3(HD / 64, ED / 64, NLAYER), 256, 0, stream>>>(
      Wsd, wd_t, ED, HD, 1, NEXPA, NEXP);
  k_wrtrans<<<NLAYER, 256, 0, stream>>>(Wr, wr_t);

  k_embed_ln<<<BT, 256, 0, stream>>>(x, W_emb, W_pos, ln1_g, ln1_b, hbuf, lno_bf);

  for (int l = 0; l < NLAYER; ++l) {
    k_mgemm<0, 1><<<dim3(24, 32), 256, 0, stream>>>(
        lno_bf, wqkv_t + (size_t)l * HD * 3 * HD, nullptr, nullptr, qkv_bf, BT, 3 * HD, HD);
    k_vtrans<<<dim3(64, 16), 256, 0, stream>>>(qkv_bf, vtb);
    k_mattn<<<dim3(64, 8), 256, 0, stream>>>(qkv_bf, vtb, ybf);
    k_mgemm64<2, 1><<<dim3(16, 32), 256, 0, stream>>>(
        ybf, wo_t + (size_t)l * HD * HD, hbuf, nullptr, ab_bf, BT, HD, HD);
    k_ln_router<<<BT, 256, 0, stream>>>(ab_bf, ln2_g + (size_t)l * HD, ln2_b + (size_t)l * HD,
                                        wr_t + (size_t)l * NEXP * HD, lno_bf, gates, eidx);
    k_hist<<<NSB, 1024, 0, stream>>>(eidx, hist_g);
    k_scatter2<<<NSB, 1024, 0, stream>>>(eidx, gates, hist_g, counts, offs,
                                         row_slot, gate_slot, slot_of);
    // grouped experts: 10 routed + shared(#10), one up + one down GEMM
    k_mgemm_moe64<1><<<dim3(8, 160), 256, 0, stream>>>(
        lno_bf, wu_t + (size_t)l * NEXPA * HD * ED, rup_bf,
        counts, offs, row_slot, gate_slot, ED, HD, 1);
    k_mgemm_moe64<3><<<dim3(16, 160), 256, 0, stream>>>(
        rup_bf, wd_t + (size_t)l * NEXPA * ED * HD, rd_bf,
        counts, offs, row_slot, gate_slot, HD, ED, 0);
    if (l < NLAYER - 1) {
      k_combine_ln<1><<<BT, 256, 0, stream>>>(hbuf, rd_bf, slot_of,
                                              ln1_g + (size_t)(l + 1) * HD,
                                              ln1_b + (size_t)(l + 1) * HD, lno_bf);
    } else {
      k_combine_ln<0><<<BT, 256, 0, stream>>>(hbuf, rd_bf, slot_of,
                                              nullptr, nullptr, nullptr);
    }
  }

  k_lnf<<<4, 256, 0, stream>>>(hbuf, lnf_g, lnf_b, hf);
  k_head<<<NVOCAB / 16, 256, 0, stream>>>(hf, W_emb, out);
}

// Round 12
// 1006.395 us; speedup vs baseline: 1.0183x; 1.0183x over previous
//
#include <hip/hip_runtime.h>
#include <hip/hip_bf16.h>
#include <math.h>

#define BT 4096      // B*T tokens
#define HD 1024      // hidden
#define NHEAD 16
#define DH 64
#define ED 512       // expert dim
#define NEXP 10
#define NEXPA 11     // incl. shared expert as #10
#define TOPKE 3
#define NLAYER 4
#define NVOCAB 32000
#define NSLOT (BT * TOPKE)   // 12288 routed slots
#define NSLOTA (NSLOT + BT)  // + 4096 shared slots = 16384
#define NSB 12               // setup blocks (NSLOT / 1024)

typedef __attribute__((ext_vector_type(8))) short bf16x8;
typedef __attribute__((ext_vector_type(4))) short bf16x4;
typedef __attribute__((ext_vector_type(4))) float f32x4;

__device__ __forceinline__ float gelu_f(float x) {
  return 0.5f * x * (1.0f + erff(x * 0.70710678118654752440f));
}

// async global->LDS, 16B per lane, 64 lanes = 1KB per call.
__device__ __forceinline__ void gll16(const void* g, void* l) {
  __builtin_amdgcn_global_load_lds(
      (const __attribute__((address_space(1))) unsigned int*)g,
      (__attribute__((address_space(3))) unsigned int*)l, 16, 0, 0);
}

// counted-vmcnt barrier primitives (T4): leave prefetch loads in flight
#define VMWAIT4() asm volatile("s_waitcnt vmcnt(4)" ::: "memory")
#define VMWAIT3() asm volatile("s_waitcnt vmcnt(3)" ::: "memory")
#define VMWAIT0() asm volatile("s_waitcnt vmcnt(0)" ::: "memory")
#define BAR() __builtin_amdgcn_s_barrier()
#define SCHEDB() __builtin_amdgcn_sched_barrier(0)

// ---------------- embed + LN1(layer0): h = W_emb[x]+W_pos; lno_bf = LN(h) ----
__global__ __launch_bounds__(256) void k_embed_ln(const int* __restrict__ x,
                                                  const float* __restrict__ Wemb,
                                                  const float* __restrict__ Wpos,
                                                  const float* __restrict__ g,
                                                  const float* __restrict__ b,
                                                  float* __restrict__ h,
                                                  __hip_bfloat16* __restrict__ outb) {
  const int t = blockIdx.x;
  const int tid = threadIdx.x;
  const int pos = t & 1023;
  const int tok = x[t];
  float4 a = ((const float4*)(Wemb + (size_t)tok * HD))[tid];
  float4 p = ((const float4*)(Wpos + (size_t)pos * HD))[tid];
  float4 v = make_float4(a.x + p.x, a.y + p.y, a.z + p.z, a.w + p.w);
  ((float4*)(h + (size_t)t * HD))[tid] = v;
  float s = v.x + v.y + v.z + v.w;
  float ss = v.x * v.x + v.y * v.y + v.z * v.z + v.w * v.w;
#pragma unroll
  for (int o = 32; o > 0; o >>= 1) { s += __shfl_down(s, o); ss += __shfl_down(ss, o); }
  __shared__ float rs[4], rss[4];
  if ((tid & 63) == 0) { rs[tid >> 6] = s; rss[tid >> 6] = ss; }
  __syncthreads();
  const float S = rs[0] + rs[1] + rs[2] + rs[3];
  const float SS = rss[0] + rss[1] + rss[2] + rss[3];
  const float mean = S * (1.0f / HD);
  const float inv = rsqrtf(SS * (1.0f / HD) - mean * mean + 1e-5f);
  const float4 gg = ((const float4*)g)[tid];
  const float4 bb = ((const float4*)b)[tid];
  union { bf16x4 v; __hip_bfloat16 e[4]; } u;
  u.e[0] = __float2bfloat16((v.x - mean) * inv * gg.x + bb.x);
  u.e[1] = __float2bfloat16((v.y - mean) * inv * gg.y + bb.y);
  u.e[2] = __float2bfloat16((v.z - mean) * inv * gg.z + bb.z);
  u.e[3] = __float2bfloat16((v.w - mean) * inv * gg.w + bb.w);
  *(bf16x4*)(outb + (size_t)t * HD + tid * 4) = u.v;
}

// ---------------- weight transpose + fp32->bf16: [z][K][N] -> [z'][N][K] -----
__global__ __launch_bounds__(256) void k_wtrans(const float* __restrict__ in,
                                                __hip_bfloat16* __restrict__ out,
                                                int K, int N,
                                                int srcPer, int dstPer, int dstOff) {
  const int z = blockIdx.z;
  const int dz = (z / srcPer) * dstPer + (z % srcPer) + dstOff;
  const float* src = in + (size_t)z * K * N;
  __hip_bfloat16* dst = out + (size_t)dz * N * K;
  __shared__ float t[64][65];
  const int tid = threadIdx.x;
  const int k0 = blockIdx.y * 64, n0 = blockIdx.x * 64;
#pragma unroll
  for (int i = 0; i < 4; ++i) {
    const int r = (tid >> 4) + i * 16;
    const int c = (tid & 15) * 4;
    float4 v = *(const float4*)(src + (size_t)(k0 + r) * N + n0 + c);
    t[r][c] = v.x; t[r][c + 1] = v.y; t[r][c + 2] = v.z; t[r][c + 3] = v.w;
  }
  __syncthreads();
#pragma unroll
  for (int i = 0; i < 2; ++i) {
    const int n = (tid >> 3) + i * 32;
    const int k = (tid & 7) * 8;
    union { bf16x8 v; __hip_bfloat16 e[8]; } u;
#pragma unroll
    for (int j = 0; j < 8; ++j) u.e[j] = __float2bfloat16(t[k + j][n]);
    *(bf16x8*)(dst + (size_t)(n0 + n) * K + k0 + k) = u.v;
  }
}

// ---------------- router weight transpose: Wr [L][HD][NEXP] -> [L][NEXP][HD] --
__global__ __launch_bounds__(256) void k_wrtrans(const float* __restrict__ in,
                                                 float* __restrict__ out) {
  const int l = blockIdx.x;
  const float* src = in + (size_t)l * HD * NEXP;
  float* dst = out + (size_t)l * NEXP * HD;
  for (int idx = threadIdx.x; idx < NEXP * HD; idx += 256) {
    const int e = idx / HD, k = idx - e * HD;
    dst[idx] = src[(size_t)k * NEXP + e];
  }
}

// ---------------- fused LN2 + router (bf16 input) ----------------
__global__ __launch_bounds__(256) void k_ln_router(const __hip_bfloat16* __restrict__ in,
                                                   const float* __restrict__ g,
                                                   const float* __restrict__ b,
                                                   const float* __restrict__ Wrt,
                                                   __hip_bfloat16* __restrict__ outb,
                                                   float* __restrict__ gates,
                                                   int* __restrict__ eidx) {
  const int row = blockIdx.x;
  const int tid = threadIdx.x;
  __shared__ float xs[HD];
  __shared__ float rs[4], rss[4];
  __shared__ float lg[16];
  union { bf16x4 v; __hip_bfloat16 e[4]; } iv;
  iv.v = *(const bf16x4*)(in + (size_t)row * HD + tid * 4);
  const float4 v = make_float4(__bfloat162float(iv.e[0]), __bfloat162float(iv.e[1]),
                               __bfloat162float(iv.e[2]), __bfloat162float(iv.e[3]));
  float s = v.x + v.y + v.z + v.w;
  float ss = v.x * v.x + v.y * v.y + v.z * v.z + v.w * v.w;
#pragma unroll
  for (int o = 32; o > 0; o >>= 1) { s += __shfl_down(s, o); ss += __shfl_down(ss, o); }
  if ((tid & 63) == 0) { rs[tid >> 6] = s; rss[tid >> 6] = ss; }
  __syncthreads();
  const float S = rs[0] + rs[1] + rs[2] + rs[3];
  const float SS = rss[0] + rss[1] + rss[2] + rss[3];
  const float mean = S * (1.0f / HD);
  const float inv = rsqrtf(SS * (1.0f / HD) - mean * mean + 1e-5f);
  const float4 gg = ((const float4*)g)[tid];
  const float4 bb = ((const float4*)b)[tid];
  const float o0 = (v.x - mean) * inv * gg.x + bb.x;
  const float o1 = (v.y - mean) * inv * gg.y + bb.y;
  const float o2 = (v.z - mean) * inv * gg.z + bb.z;
  const float o3 = (v.w - mean) * inv * gg.w + bb.w;
  union { bf16x4 v; __hip_bfloat16 e[4]; } u;
  u.e[0] = __float2bfloat16(o0); u.e[1] = __float2bfloat16(o1);
  u.e[2] = __float2bfloat16(o2); u.e[3] = __float2bfloat16(o3);
  *(bf16x4*)(outb + (size_t)row * HD + tid * 4) = u.v;
  ((float4*)xs)[tid] = make_float4(o0, o1, o2, o3);
  __syncthreads();
  const int wv = tid >> 6, lane = tid & 63;
  for (int e = wv; e < NEXP; e += 4) {
    const float4* wr4 = (const float4*)(Wrt + (size_t)e * HD);
    float d = 0.f;
#pragma unroll
    for (int i = 0; i < 4; ++i) {
      float4 xv = ((const float4*)xs)[lane + i * 64];
      float4 wv4 = wr4[lane + i * 64];
      d += xv.x * wv4.x + xv.y * wv4.y + xv.z * wv4.z + xv.w * wv4.w;
    }
#pragma unroll
    for (int o = 32; o > 0; o >>= 1) d += __shfl_down(d, o);
    if (lane == 0) lg[e] = d;
  }
  __syncthreads();
  if (tid == 0) {
    float m = lg[0];
#pragma unroll
    for (int e = 1; e < NEXP; ++e) m = fmaxf(m, lg[e]);
    float p[NEXP], sum = 0.f;
#pragma unroll
    for (int e = 0; e < NEXP; ++e) { p[e] = __expf(lg[e] - m); sum += p[e]; }
    const float isum = 1.0f / sum;
#pragma unroll
    for (int e = 0; e < NEXP; ++e) p[e] *= isum;
    bool used[NEXP] = {};
    for (int k = 0; k < TOPKE; ++k) {
      int best = -1; float bv = -1.f;
      for (int e = 0; e < NEXP; ++e)
        if (!used[e] && p[e] > bv) { bv = p[e]; best = e; }
      used[best] = true;
      eidx[row * TOPKE + k] = best;
      gates[row * TOPKE + k] = bv;
    }
  }
}

// final LN over the 4 last-token rows only
__global__ __launch_bounds__(256) void k_lnf(const float* __restrict__ h,
                                             const float* __restrict__ g,
                                             const float* __restrict__ b,
                                             float* __restrict__ hf) {
  const int row = blockIdx.x * 1024 + 1023;
  const int tid = threadIdx.x;
  const float* xr = h + (size_t)row * HD;
  float s = 0.f, ss = 0.f;
  for (int i = tid; i < HD; i += 256) { float v = xr[i]; s += v; ss += v * v; }
#pragma unroll
  for (int o = 32; o > 0; o >>= 1) { s += __shfl_down(s, o); ss += __shfl_down(ss, o); }
  __shared__ float rs[4], rss[4];
  if ((tid & 63) == 0) { rs[tid >> 6] = s; rss[tid >> 6] = ss; }
  __syncthreads();
  const float S = rs[0] + rs[1] + rs[2] + rs[3];
  const float SS = rss[0] + rss[1] + rss[2] + rss[3];
  const float mean = S * (1.0f / HD);
  const float inv = rsqrtf(SS * (1.0f / HD) - mean * mean + 1e-5f);
  float* orow = hf + (size_t)blockIdx.x * HD;
  for (int i = tid; i < HD; i += 256) {
    float v = xr[i];
    orow[i] = (v - mean) * inv * g[i] + b[i];
  }
}

// ---- 128-wide tile staging/compute (QKV GEMM) ----
#define STAGE_AB(dA, dB, kk)                                  \
  do {                                                        \
    gll16(ga + (kk), &dA[(w * 32) * 32]);                     \
    gll16(ga + (size_t)16 * K + (kk), &dA[(w * 32 + 16) * 32]); \
    gll16(gb + (kk), &dB[(w * 32) * 32]);                     \
    gll16(gb + (size_t)16 * K + (kk), &dB[(w * 32 + 16) * 32]); \
  } while (0)

#define COMPUTE_AB(sA, sB)                                                        \
  do {                                                                            \
    bf16x8 af[4], bfv[4];                                                         \
    _Pragma("unroll") for (int m = 0; m < 4; ++m) af[m] = *(const bf16x8*)&sA[aidx[m]]; \
    _Pragma("unroll") for (int n = 0; n < 4; ++n) bfv[n] = *(const bf16x8*)&sB[bidx[n]]; \
    _Pragma("unroll") for (int m = 0; m < 4; ++m)                                 \
      _Pragma("unroll") for (int n = 0; n < 4; ++n)                               \
        acc[m][n] = __builtin_amdgcn_mfma_f32_16x16x32_bf16(af[m], bfv[n], acc[m][n], 0, 0, 0); \
  } while (0)

#define KLOOP(STAGER, VMW)                                     \
  do {                                                         \
    STAGER(As0, Bs0, 0);                                       \
    for (int k0 = 0; k0 < K; k0 += 64) {                       \
      STAGER(As1, Bs1, k0 + 32);                               \
      VMW(); BAR(); SCHEDB();                                  \
      COMPUTE_AB(As0, Bs0);                                    \
      BAR();                                                   \
      if (k0 + 64 < K) { STAGER(As0, Bs0, k0 + 64); VMW(); }   \
      else VMWAIT0();                                          \
      BAR(); SCHEDB();                                         \
      COMPUTE_AB(As1, Bs1);                                    \
      BAR();                                                   \
    }                                                          \
  } while (0)

// ---- 64-wide-N tile staging/compute (Wo + MoE GEMMs): 128Mx64N, 3 loads/wave --
#define STAGE64_AB(dA, dB, kk)                                \
  do {                                                        \
    gll16(ga + (kk), &dA[(w * 32) * 32]);                     \
    gll16(ga + (size_t)16 * K + (kk), &dA[(w * 32 + 16) * 32]); \
    gll16(gbn + (kk), &dB[(w * 16) * 32]);                    \
  } while (0)

#define STAGE64_AB2(dA, dB, kk)                               \
  do {                                                        \
    gll16(ga0 + (kk), &dA[(w * 32) * 32]);                    \
    gll16(ga1 + (kk), &dA[(w * 32 + 16) * 32]);               \
    gll16(gbn + (kk), &dB[(w * 16) * 32]);                    \
  } while (0)

#define COMPUTE64(sA, sB)                                                         \
  do {                                                                            \
    bf16x8 af[4], bfv[2];                                                         \
    _Pragma("unroll") for (int m = 0; m < 4; ++m) af[m] = *(const bf16x8*)&sA[aidx[m]]; \
    _Pragma("unroll") for (int n = 0; n < 2; ++n) bfv[n] = *(const bf16x8*)&sB[bidx[n]]; \
    _Pragma("unroll") for (int m = 0; m < 4; ++m)                                 \
      _Pragma("unroll") for (int n = 0; n < 2; ++n)                               \
        acc[m][n] = __builtin_amdgcn_mfma_f32_16x16x32_bf16(af[m], bfv[n], acc[m][n], 0, 0, 0); \
  } while (0)

#define KLOOP64(STAGER)                                        \
  do {                                                         \
    STAGER(As0, Bs0, 0);                                       \
    for (int k0 = 0; k0 < K; k0 += 64) {                       \
      STAGER(As1, Bs1, k0 + 32);                               \
      VMWAIT3(); BAR(); SCHEDB();                              \
      COMPUTE64(As0, Bs0);                                     \
      BAR();                                                   \
      if (k0 + 64 < K) { STAGER(As0, Bs0, k0 + 64); VMWAIT3(); } \
      else VMWAIT0();                                          \
      BAR(); SCHEDB();                                         \
      COMPUTE64(As1, Bs1);                                     \
      BAR();                                                   \
    }                                                          \
  } while (0)

// ---------------- bf16 MFMA GEMM (128x128): C = A @ Bt^T ----------------
// EPI: 0 none, 2 +residual R.  OBF: 1 -> bf16 out.  VT: V-cols (>=2048)
// written transposed to Vt[(bh*64+d)][t] (QKV fusion; block-uniform branch).
template <int EPI, int OBF, int VT>
__global__ __launch_bounds__(256) void k_mgemm(const __hip_bfloat16* __restrict__ A,
                                               const __hip_bfloat16* __restrict__ Bt,
                                               const float* __restrict__ R,
                                               float* __restrict__ C,
                                               __hip_bfloat16* __restrict__ Cb,
                                               __hip_bfloat16* __restrict__ Vt,
                                               int M, int N, int K) {
  __shared__ __hip_bfloat16 As0[128 * 32];
  __shared__ __hip_bfloat16 Bs0[128 * 32];
  __shared__ __hip_bfloat16 As1[128 * 32];
  __shared__ __hip_bfloat16 Bs1[128 * 32];
  const int tid = threadIdx.x;
  const int w = tid >> 6, lane = tid & 63;
  const int wr = w >> 1, wc = w & 1;
  const int m0 = blockIdx.y << 7, n0 = blockIdx.x << 7;
  const int srow = lane >> 2;
  const int scol = (lane & 3) * 8;
  const int kq = (lane >> 4) * 8;
  int aidx[4], bidx[4];
#pragma unroll
  for (int m = 0; m < 4; ++m) aidx[m] = (wr * 64 + m * 16 + (lane & 15)) * 32 + kq;
#pragma unroll
  for (int n = 0; n < 4; ++n) bidx[n] = (wc * 64 + n * 16 + (lane & 15)) * 32 + kq;

  f32x4 acc[4][4];
#pragma unroll
  for (int m = 0; m < 4; ++m)
#pragma unroll
    for (int n = 0; n < 4; ++n) acc[m][n] = (f32x4){0.f, 0.f, 0.f, 0.f};

  const __hip_bfloat16* ga = A + (size_t)(m0 + w * 32 + srow) * K + scol;
  const __hip_bfloat16* gb = Bt + (size_t)(n0 + w * 32 + srow) * K + scol;

  KLOOP(STAGE_AB, VMWAIT4);

#pragma unroll
  for (int m = 0; m < 4; ++m) {
    const int row0 = m0 + wr * 64 + m * 16 + (lane >> 4) * 4;
#pragma unroll
    for (int n = 0; n < 4; ++n) {
      const int col = n0 + wc * 64 + n * 16 + (lane & 15);
      if (VT && col >= 2048) {
        union { bf16x4 v; __hip_bfloat16 e[4]; } pv;
#pragma unroll
        for (int r = 0; r < 4; ++r) pv.e[r] = __float2bfloat16(acc[m][n][r]);
        const int d = col - 2048;
        const int bh = (row0 >> 10) * 16 + (d >> 6);
        *(bf16x4*)(Vt + ((size_t)(bh * 64 + (d & 63))) * 1024 + (row0 & 1023)) = pv.v;
      } else {
#pragma unroll
        for (int r = 0; r < 4; ++r) {
          const int row = row0 + r;
          float v = acc[m][n][r];
          if (EPI == 2) v += R[(size_t)row * N + col];
          if (OBF) Cb[(size_t)row * N + col] = __float2bfloat16(v);
          else C[(size_t)row * N + col] = v;
        }
      }
    }
  }
}

// ---------------- bf16 MFMA GEMM (128Mx64N): higher occupancy ----------------
template <int EPI, int OBF>
__global__ __launch_bounds__(256) void k_mgemm64(const __hip_bfloat16* __restrict__ A,
                                                 const __hip_bfloat16* __restrict__ Bt,
                                                 const float* __restrict__ R,
                                                 float* __restrict__ C,
                                                 __hip_bfloat16* __restrict__ Cb,
                                                 int M, int N, int K) {
  __shared__ __hip_bfloat16 As0[128 * 32];
  __shared__ __hip_bfloat16 Bs0[64 * 32];
  __shared__ __hip_bfloat16 As1[128 * 32];
  __shared__ __hip_bfloat16 Bs1[64 * 32];
  const int tid = threadIdx.x;
  const int w = tid >> 6, lane = tid & 63;
  const int wr = w & 1, wc = w >> 1;
  const int m0 = blockIdx.y << 7, n0 = blockIdx.x << 6;
  const int srow = lane >> 2;
  const int scol = (lane & 3) * 8;
  const int kq = (lane >> 4) * 8;
  int aidx[4], bidx[2];
#pragma unroll
  for (int m = 0; m < 4; ++m) aidx[m] = (wr * 64 + m * 16 + (lane & 15)) * 32 + kq;
#pragma unroll
  for (int n = 0; n < 2; ++n) bidx[n] = (wc * 32 + n * 16 + (lane & 15)) * 32 + kq;

  f32x4 acc[4][2];
#pragma unroll
  for (int m = 0; m < 4; ++m)
#pragma unroll
    for (int n = 0; n < 2; ++n) acc[m][n] = (f32x4){0.f, 0.f, 0.f, 0.f};

  const __hip_bfloat16* ga = A + (size_t)(m0 + w * 32 + srow) * K + scol;
  const __hip_bfloat16* gbn = Bt + (size_t)(n0 + w * 16 + srow) * K + scol;

  KLOOP64(STAGE64_AB);

#pragma unroll
  for (int m = 0; m < 4; ++m) {
#pragma unroll
    for (int n = 0; n < 2; ++n) {
#pragma unroll
      for (int r = 0; r < 4; ++r) {
        const int row = m0 + wr * 64 + m * 16 + (lane >> 4) * 4 + r;
        const int col = n0 + wc * 32 + n * 16 + (lane & 15);
        float v = acc[m][n][r];
        if (EPI == 2) v += R[(size_t)row * N + col];
        if (OBF) Cb[(size_t)row * N + col] = __float2bfloat16(v);
        else C[(size_t)row * N + col] = v;
      }
    }
  }
}

// ---------------- grouped MoE GEMM (128Mx64N) over 11 experts ----------------
// EPI: 1 = gelu (up), 3 = gate-scale (down). Tile derived from counts scan.
template <int EPI>
__global__ __launch_bounds__(256) void k_mgemm_moe64(const __hip_bfloat16* __restrict__ A,
                                                     const __hip_bfloat16* __restrict__ Btbase,
                                                     __hip_bfloat16* __restrict__ Cb,
                                                     const int* __restrict__ counts,
                                                     const int* __restrict__ offs,
                                                     const int* __restrict__ row_slot,
                                                     const float* __restrict__ gate_slot,
                                                     int N, int K, int gather) {
  int T = blockIdx.y;
  int e = -1, r0 = 0, acc0 = 0;
#pragma unroll
  for (int ee = 0; ee < NEXPA; ++ee) {
    const int nt = (counts[ee] + 127) >> 7;
    if (e < 0 && T < acc0 + nt) { e = ee; r0 = (T - acc0) << 7; }
    acc0 += nt;
  }
  if (e < 0) return;
  const int cnt = counts[e], off = offs[e];
  const __hip_bfloat16* Bt = Btbase + (size_t)e * N * K;

  __shared__ __hip_bfloat16 As0[128 * 32];
  __shared__ __hip_bfloat16 Bs0[64 * 32];
  __shared__ __hip_bfloat16 As1[128 * 32];
  __shared__ __hip_bfloat16 Bs1[64 * 32];
  const int tid = threadIdx.x;
  const int w = tid >> 6, lane = tid & 63;
  const int wr = w & 1, wc = w >> 1;
  const int n0 = blockIdx.x << 6;
  const int srow = lane >> 2;
  const int scol = (lane & 3) * 8;
  const int kq = (lane >> 4) * 8;
  int aidx[4], bidx[2];
#pragma unroll
  for (int m = 0; m < 4; ++m) aidx[m] = (wr * 64 + m * 16 + (lane & 15)) * 32 + kq;
#pragma unroll
  for (int n = 0; n < 2; ++n) bidx[n] = (wc * 32 + n * 16 + (lane & 15)) * 32 + kq;

  const int last = off + cnt - 1;
  int s0 = off + r0 + w * 32 + srow;        if (s0 > last) s0 = last;
  int s1 = off + r0 + w * 32 + 16 + srow;   if (s1 > last) s1 = last;
  const int arow0 = gather ? row_slot[s0] : s0;
  const int arow1 = gather ? row_slot[s1] : s1;

  f32x4 acc[4][2];
#pragma unroll
  for (int m = 0; m < 4; ++m)
#pragma unroll
    for (int n = 0; n < 2; ++n) acc[m][n] = (f32x4){0.f, 0.f, 0.f, 0.f};

  const __hip_bfloat16* ga0 = A + (size_t)arow0 * K + scol;
  const __hip_bfloat16* ga1 = A + (size_t)arow1 * K + scol;
  const __hip_bfloat16* gbn = Bt + (size_t)(n0 + w * 16 + srow) * K + scol;

  KLOOP64(STAGE64_AB2);

#pragma unroll
  for (int m = 0; m < 4; ++m) {
#pragma unroll
    for (int r = 0; r < 4; ++r) {
      const int rl = wr * 64 + m * 16 + (lane >> 4) * 4 + r;
      if (r0 + rl < cnt) {
        const int slot = off + r0 + rl;
        const float sc = (EPI == 3) ? gate_slot[slot] : 1.0f;
#pragma unroll
        for (int n = 0; n < 2; ++n) {
          const int col = n0 + wc * 32 + n * 16 + (lane & 15);
          float v = acc[m][n][r];
          if (EPI == 1) v = gelu_f(v);
          else v *= sc;
          Cb[(size_t)slot * N + col] = __float2bfloat16(v);
        }
      }
    }
  }
}

// ---------------- MFMA flash attention (swapped QK^T), 128 q rows / block -----
// T14 async-STAGE split + T5 setprio.
__global__ __launch_bounds__(256) void k_mattn(const __hip_bfloat16* __restrict__ qkv,
                                               const __hip_bfloat16* __restrict__ vt,
                                               __hip_bfloat16* __restrict__ y) {
  const int bh = blockIdx.x;
  const int qt = 7 - (int)blockIdx.y;          // big causal blocks first
  const int b = bh >> 4, hh = bh & 15;
  const int tid = threadIdx.x;
  const int w = tid >> 6, lane = tid & 63;
  const int l15 = lane & 15, g = lane >> 4;
  const int swl = (l15 & 7) << 3;

  __shared__ __hip_bfloat16 Ks[64 * 64];
  __shared__ __hip_bfloat16 Vs[64 * 64];
  __shared__ __hip_bfloat16 Pw[2][4][16 * 64];

  const int srow = tid >> 3;             // 0..31
  const int scc = (tid & 7) * 8;
  const int ssw = scc ^ ((srow & 7) << 3);
  bf16x8 kreg[2], vreg[2];

#define LOADT(kt)                                                                  \
  do {                                                                             \
    _Pragma("unroll") for (int i = 0; i < 2; ++i) {                                \
      const int r = i * 32 + srow;                                                 \
      kreg[i] = *(const bf16x8*)(qkv +                                             \
          ((size_t)(b * 1024 + (kt) * 64 + r)) * 3072 + 1024 + hh * 64 + scc);     \
      vreg[i] = *(const bf16x8*)(vt +                                              \
          ((size_t)(bh * 64 + r)) * 1024 + (kt) * 64 + scc);                       \
    }                                                                              \
  } while (0)

#define WRITET()                                                                   \
  do {                                                                             \
    _Pragma("unroll") for (int i = 0; i < 2; ++i) {                                \
      const int r = i * 32 + srow;                                                 \
      *(bf16x8*)&Ks[r * 64 + ssw] = kreg[i];                                       \
      *(bf16x8*)&Vs[r * 64 + ssw] = vreg[i];                                       \
    }                                                                              \
  } while (0)

  bf16x8 qf[2][2];
#pragma unroll
  for (int s = 0; s < 2; ++s) {
    const __hip_bfloat16* qp =
        qkv + ((size_t)(b * 1024 + qt * 128 + s * 64 + w * 16 + l15)) * 3072 + hh * 64 + g * 8;
    qf[s][0] = *(const bf16x8*)qp;
    qf[s][1] = *(const bf16x8*)(qp + 32);
  }

  f32x4 yacc[2][4];
#pragma unroll
  for (int s = 0; s < 2; ++s)
#pragma unroll
    for (int nt = 0; nt < 4; ++nt) yacc[s][nt] = (f32x4){0.f, 0.f, 0.f, 0.f};
  float m_s[2] = {-INFINITY, -INFINITY};
  float l_s[2] = {0.f, 0.f};
  const int qg0 = qt * 128 + w * 16 + l15;

  const int ktmax = 2 * qt + 1;
  LOADT(0);
  WRITET();
  __syncthreads();

  for (int kt = 0; kt <= ktmax; ++kt) {
    if (kt < ktmax) LOADT(kt + 1);

    bf16x8 kf[4][2];
#pragma unroll
    for (int m = 0; m < 4; ++m) {
      const int row = m * 16 + l15;
#pragma unroll
      for (int kk = 0; kk < 2; ++kk)
        kf[m][kk] = *(const bf16x8*)&Ks[row * 64 + ((kk * 32 + g * 8) ^ swl)];
    }
    bf16x8 pa[2][2] = {};
#pragma unroll
    for (int s = 0; s < 2; ++s) {
      if (kt > 2 * qt + s) continue;
      f32x4 st[4];
#pragma unroll
      for (int m = 0; m < 4; ++m) st[m] = (f32x4){0.f, 0.f, 0.f, 0.f};
      __builtin_amdgcn_s_setprio(1);
#pragma unroll
      for (int m = 0; m < 4; ++m)
#pragma unroll
        for (int kk = 0; kk < 2; ++kk)
          st[m] = __builtin_amdgcn_mfma_f32_16x16x32_bf16(kf[m][kk], qf[s][kk], st[m], 0, 0, 0);
      __builtin_amdgcn_s_setprio(0);
      const int qg = qg0 + s * 64;
      const bool dia = (kt == 2 * qt + s);
      float tmax = -INFINITY;
#pragma unroll
      for (int m = 0; m < 4; ++m)
#pragma unroll
        for (int r = 0; r < 4; ++r) {
          float v = st[m][r] * 0.125f;
          if (dia && (kt * 64 + m * 16 + g * 4 + r) > qg) v = -INFINITY;
          st[m][r] = v;
          tmax = fmaxf(tmax, v);
        }
      tmax = fmaxf(tmax, __shfl_xor(tmax, 16));
      tmax = fmaxf(tmax, __shfl_xor(tmax, 32));
      const float mnew = fmaxf(m_s[s], tmax);
      const float fac = __expf(m_s[s] - mnew);
      m_s[s] = mnew;
      float tsum = 0.f;
#pragma unroll
      for (int m = 0; m < 4; ++m)
#pragma unroll
        for (int r = 0; r < 4; ++r) {
          float p = __expf(st[m][r] - mnew);
          st[m][r] = p;
          tsum += p;
        }
      tsum += __shfl_xor(tsum, 16);
      tsum += __shfl_xor(tsum, 32);
      l_s[s] = l_s[s] * fac + tsum;
      float fq[4];
#pragma unroll
      for (int r = 0; r < 4; ++r) fq[r] = __shfl(fac, g * 4 + r);
#pragma unroll
      for (int nt = 0; nt < 4; ++nt)
#pragma unroll
        for (int r = 0; r < 4; ++r) yacc[s][nt][r] *= fq[r];
#pragma unroll
      for (int m = 0; m < 4; ++m) {
        union { bf16x4 v; __hip_bfloat16 e[4]; } pk;
#pragma unroll
        for (int r = 0; r < 4; ++r) pk.e[r] = __float2bfloat16(st[m][r]);
        *(bf16x4*)&Pw[s][w][l15 * 64 + ((m * 16 + g * 4) ^ swl)] = pk.v;
      }
#pragma unroll
      for (int kk = 0; kk < 2; ++kk)
        pa[s][kk] = *(const bf16x8*)&Pw[s][w][l15 * 64 + ((kk * 32 + g * 8) ^ swl)];
    }
    const bool v0 = (kt <= 2 * qt);
    __builtin_amdgcn_s_setprio(1);
#pragma unroll
    for (int kk = 0; kk < 2; ++kk)
#pragma unroll
      for (int nt = 0; nt < 4; ++nt) {
        bf16x8 vf = *(const bf16x8*)&Vs[(nt * 16 + l15) * 64 + ((kk * 32 + g * 8) ^ swl)];
        if (v0) yacc[0][nt] = __builtin_amdgcn_mfma_f32_16x16x32_bf16(pa[0][kk], vf, yacc[0][nt], 0, 0, 0);
        yacc[1][nt] = __builtin_amdgcn_mfma_f32_16x16x32_bf16(pa[1][kk], vf, yacc[1][nt], 0, 0, 0);
      }
    __builtin_amdgcn_s_setprio(0);

    if (kt < ktmax) {
      __syncthreads();
      WRITET();
      __syncthreads();
    }
  }
#pragma unroll
  for (int s = 0; s < 2; ++s) {
    const float inv = 1.0f / l_s[s];
    float iq[4];
#pragma unroll
    for (int r = 0; r < 4; ++r) iq[r] = __shfl(inv, g * 4 + r);
#pragma unroll
    for (int r = 0; r < 4; ++r) {
      __hip_bfloat16* yp =
          y + ((size_t)(b * 1024 + qt * 128 + s * 64 + w * 16 + g * 4 + r)) * HD + hh * 64 + l15;
#pragma unroll
      for (int nt = 0; nt < 4; ++nt)
        yp[nt * 16] = __float2bfloat16(yacc[s][nt][r] * iq[r]);
    }
  }
#undef LOADT
#undef WRITET
}

// ---------------- MoE setup, single kernel: full hist per block + scatter -----
__global__ __launch_bounds__(1024) void k_moesetup2(const int* __restrict__ eidx,
                                                    const float* __restrict__ gates,
                                                    int* __restrict__ counts,
                                                    int* __restrict__ offs,
                                                    int* __restrict__ row_slot,
                                                    float* __restrict__ gate_slot,
                                                    int* __restrict__ slot_of) {
  __shared__ int lh[NSB][16];
  __shared__ int lcur[16];
  const int tid = threadIdx.x;
  const int blk = blockIdx.x;
  if (tid < NSB * 16) lh[tid >> 4][tid & 15] = 0;
  __syncthreads();
#pragma unroll
  for (int c = 0; c < NSB; ++c) atomicAdd(&lh[c][eidx[c * 1024 + tid]], 1);
  __syncthreads();
  if (tid == 0) {
    int off = 0;
    for (int e = 0; e < NEXP; ++e) {
      int pre = 0, tot = 0;
      for (int b2 = 0; b2 < NSB; ++b2) {
        if (b2 < blk) pre += lh[b2][e];
        tot += lh[b2][e];
      }
      lcur[e] = off + pre;
      if (blk == 0) { counts[e] = tot; offs[e] = off; }
      off += tot;
    }
    if (blk == 0) { counts[NEXP] = BT; offs[NEXP] = NSLOT; }
  }
  __syncthreads();
  const int i = blk * 1024 + tid;
  const int e = eidx[i];
  const int pos = atomicAdd(&lcur[e], 1);
  row_slot[pos] = i / TOPKE;
  gate_slot[pos] = gates[i];
  slot_of[i] = pos;
  if (i < BT) { row_slot[NSLOT + i] = i; gate_slot[NSLOT + i] = 1.0f; }
}

// ---------------- combine (+ next-layer LN1): h += 3 routed + shared ----------
template <int DOLN>
__global__ __launch_bounds__(256) void k_combine_ln(float* __restrict__ h,
                                                    const __hip_bfloat16* __restrict__ rd,
                                                    const int* __restrict__ slot_of,
                                                    const float* __restrict__ g,
                                                    const float* __restrict__ b,
                                                    __hip_bfloat16* __restrict__ outb) {
  const int t = blockIdx.x;
  const int tid = threadIdx.x;
  const int s0 = slot_of[t * 3 + 0], s1 = slot_of[t * 3 + 1], s2 = slot_of[t * 3 + 2];
  const int s3 = NSLOT + t;
  float4 hv = ((float4*)(h + (size_t)t * HD))[tid];
  union { bf16x4 v; __hip_bfloat16 e[4]; } r0, r1, r2, r3;
  r0.v = *(const bf16x4*)(rd + (size_t)s0 * HD + tid * 4);
  r1.v = *(const bf16x4*)(rd + (size_t)s1 * HD + tid * 4);
  r2.v = *(const bf16x4*)(rd + (size_t)s2 * HD + tid * 4);
  r3.v = *(const bf16x4*)(rd + (size_t)s3 * HD + tid * 4);
  hv.x += __bfloat162float(r0.e[0]) + __bfloat162float(r1.e[0]) + __bfloat162float(r2.e[0]) + __bfloat162float(r3.e[0]);
  hv.y += __bfloat162float(r0.e[1]) + __bfloat162float(r1.e[1]) + __bfloat162float(r2.e[1]) + __bfloat162float(r3.e[1]);
  hv.z += __bfloat162float(r0.e[2]) + __bfloat162float(r1.e[2]) + __bfloat162float(r2.e[2]) + __bfloat162float(r3.e[2]);
  hv.w += __bfloat162float(r0.e[3]) + __bfloat162float(r1.e[3]) + __bfloat162float(r2.e[3]) + __bfloat162float(r3.e[3]);
  ((float4*)(h + (size_t)t * HD))[tid] = hv;
  if (DOLN) {
    float s = hv.x + hv.y + hv.z + hv.w;
    float ss = hv.x * hv.x + hv.y * hv.y + hv.z * hv.z + hv.w * hv.w;
#pragma unroll
    for (int o = 32; o > 0; o >>= 1) { s += __shfl_down(s, o); ss += __shfl_down(ss, o); }
    __shared__ float rs[4], rss[4];
    if ((tid & 63) == 0) { rs[tid >> 6] = s; rss[tid >> 6] = ss; }
    __syncthreads();
    const float S = rs[0] + rs[1] + rs[2] + rs[3];
    const float SS = rss[0] + rss[1] + rss[2] + rss[3];
    const float mean = S * (1.0f / HD);
    const float inv = rsqrtf(SS * (1.0f / HD) - mean * mean + 1e-5f);
    const float4 gg = ((const float4*)g)[tid];
    const float4 bb = ((const float4*)b)[tid];
    union { bf16x4 v; __hip_bfloat16 e[4]; } u;
    u.e[0] = __float2bfloat16((hv.x - mean) * inv * gg.x + bb.x);
    u.e[1] = __float2bfloat16((hv.y - mean) * inv * gg.y + bb.y);
    u.e[2] = __float2bfloat16((hv.z - mean) * inv * gg.z + bb.z);
    u.e[3] = __float2bfloat16((hv.w - mean) * inv * gg.w + bb.w);
    *(bf16x4*)(outb + (size_t)t * HD + tid * 4) = u.v;
  }
}

// ---------------- tied head: logits[b][v] = dot(hf[b], Wemb[v]) ----------------
__global__ __launch_bounds__(256) void k_head(const float* __restrict__ hf,
                                              const float* __restrict__ Wemb,
                                              float* __restrict__ out) {
  __shared__ float hs[4][HD];
  const int tid = threadIdx.x;
  for (int i = tid; i < HD; i += 256) {
    hs[0][i] = hf[i]; hs[1][i] = hf[HD + i];
    hs[2][i] = hf[2 * HD + i]; hs[3][i] = hf[3 * HD + i];
  }
  __syncthreads();
  const int w = tid >> 6, lane = tid & 63;
  for (int i = 0; i < 4; ++i) {
    const int v = blockIdx.x * 16 + w * 4 + i;
    const float4* wr = (const float4*)(Wemb + (size_t)v * HD);
    float a0 = 0.f, a1 = 0.f, a2 = 0.f, a3 = 0.f;
    for (int q = lane; q < HD / 4; q += 64) {
      float4 wv = wr[q];
      const int k = q * 4;
      a0 += wv.x * hs[0][k] + wv.y * hs[0][k + 1] + wv.z * hs[0][k + 2] + wv.w * hs[0][k + 3];
      a1 += wv.x * hs[1][k] + wv.y * hs[1][k + 1] + wv.z * hs[1][k + 2] + wv.w * hs[1][k + 3];
      a2 += wv.x * hs[2][k] + wv.y * hs[2][k + 1] + wv.z * hs[2][k + 2] + wv.w * hs[2][k + 3];
      a3 += wv.x * hs[3][k] + wv.y * hs[3][k + 1] + wv.z * hs[3][k + 2] + wv.w * hs[3][k + 3];
    }
#pragma unroll
    for (int o = 32; o > 0; o >>= 1) {
      a0 += __shfl_down(a0, o); a1 += __shfl_down(a1, o);
      a2 += __shfl_down(a2, o); a3 += __shfl_down(a3, o);
    }
    if (lane == 0) {
      out[v] = a0; out[NVOCAB + v] = a1;
      out[2 * NVOCAB + v] = a2; out[3 * NVOCAB + v] = a3;
    }
  }
}

extern "C" void kernel_launch(void* const* d_in, const int* in_sizes, int n_in,
                              void* d_out, int out_size, void* d_ws, size_t ws_size,
                              hipStream_t stream) {
  (void)in_sizes; (void)n_in; (void)out_size; (void)ws_size;
  const int* x = (const int*)d_in[0];
  const float* W_emb = (const float*)d_in[1];
  const float* W_pos = (const float*)d_in[2];
  const float* ln1_g = (const float*)d_in[3];
  const float* ln1_b = (const float*)d_in[4];
  const float* Wqkv = (const float*)d_in[5];
  const float* Wo = (const float*)d_in[6];
  const float* ln2_g = (const float*)d_in[7];
  const float* ln2_b = (const float*)d_in[8];
  const float* Wr = (const float*)d_in[9];
  const float* Wsu = (const float*)d_in[10];
  const float* Wsd = (const float*)d_in[11];
  const float* Wu = (const float*)d_in[12];
  const float* Wd = (const float*)d_in[13];
  const float* lnf_g = (const float*)d_in[14];
  const float* lnf_b = (const float*)d_in[15];
  float* out = (float*)d_out;

  float* wsf = (float*)d_ws;
  size_t o = 0;
  float* hbuf = wsf + o; o += (size_t)BT * HD;
  float* hf = wsf + o; o += 4 * HD;
  float* gates = wsf + o; o += NSLOT;
  float* gate_slot = wsf + o; o += NSLOTA;
  int* eidx = (int*)(wsf + o); o += NSLOT;
  int* row_slot = (int*)(wsf + o); o += NSLOTA;
  int* slot_of = (int*)(wsf + o); o += NSLOT;
  int* counts = (int*)(wsf + o); o += 16;
  int* offs = (int*)(wsf + o); o += 16;
  float* wr_t = wsf + o; o += (size_t)NLAYER * NEXP * HD;
  // bf16 regions (2 bf16 per float slot)
  __hip_bfloat16* ab_bf  = (__hip_bfloat16*)(wsf + o); o += (size_t)BT * HD / 2;
  __hip_bfloat16* lno_bf = (__hip_bfloat16*)(wsf + o); o += (size_t)BT * HD / 2;
  __hip_bfloat16* ybf    = (__hip_bfloat16*)(wsf + o); o += (size_t)BT * HD / 2;
  __hip_bfloat16* rup_bf = (__hip_bfloat16*)(wsf + o); o += (size_t)NSLOTA * ED / 2;
  // qkv/vt region; later reused as rd_bf
  float* qkvreg = wsf + o; o += (size_t)BT * 3 * HD + (size_t)BT * HD / 2;
  __hip_bfloat16* wqkv_t = (__hip_bfloat16*)(wsf + o); o += (size_t)NLAYER * HD * 3 * HD / 2;
  __hip_bfloat16* wo_t   = (__hip_bfloat16*)(wsf + o); o += (size_t)NLAYER * HD * HD / 2;
  __hip_bfloat16* wu_t   = (__hip_bfloat16*)(wsf + o); o += (size_t)NLAYER * NEXPA * HD * ED / 2;
  __hip_bfloat16* wd_t   = (__hip_bfloat16*)(wsf + o); o += (size_t)NLAYER * NEXPA * ED * HD / 2;
  __hip_bfloat16* qkv_bf = (__hip_bfloat16*)qkvreg;     // BT*3HD bf16 (Q/K only used)
  __hip_bfloat16* vtb = qkv_bf + (size_t)BT * 3 * HD;   // BT*HD bf16
  __hip_bfloat16* rd_bf = (__hip_bfloat16*)qkvreg;      // NSLOTA*HD bf16, after attn

  // weight transpose+convert: [z][K][N] fp32 -> [z'][N][K] bf16
  k_wtrans<<<dim3(3 * HD / 64, HD / 64, NLAYER), 256, 0, stream>>>(
      Wqkv, wqkv_t, HD, 3 * HD, 1, 1, 0);
  k_wtrans<<<dim3(HD / 64, HD / 64, NLAYER), 256, 0, stream>>>(
      Wo, wo_t, HD, HD, 1, 1, 0);
  k_wtrans<<<dim3(ED / 64, HD / 64, NLAYER * NEXP), 256, 0, stream>>>(
      Wu, wu_t, HD, ED, NEXP, NEXPA, 0);
  k_wtrans<<<dim3(ED / 64, HD / 64, NLAYER), 256, 0, stream>>>(
      Wsu, wu_t, HD, ED, 1, NEXPA, NEXP);
  k_wtrans<<<dim3(HD / 64, ED / 64, NLAYER * NEXP), 256, 0, stream>>>(
      Wd, wd_t, ED, HD, NEXP, NEXPA, 0);
  k_wtrans<<<dim3(HD / 64, ED / 64, NLAYER), 256, 0, stream>>>(
      Wsd, wd_t, ED, HD, 1, NEXPA, NEXP);
  k_wrtrans<<<NLAYER, 256, 0, stream>>>(Wr, wr_t);

  k_embed_ln<<<BT, 256, 0, stream>>>(x, W_emb, W_pos, ln1_g, ln1_b, hbuf, lno_bf);

  for (int l = 0; l < NLAYER; ++l) {
    // QKV GEMM; V columns written directly transposed into vtb (VT=1)
    k_mgemm<0, 1, 1><<<dim3(24, 32), 256, 0, stream>>>(
        lno_bf, wqkv_t + (size_t)l * HD * 3 * HD, nullptr, nullptr, qkv_bf, vtb,
        BT, 3 * HD, HD);
    k_mattn<<<dim3(64, 8), 256, 0, stream>>>(qkv_bf, vtb, ybf);
    k_mgemm64<2, 1><<<dim3(16, 32), 256, 0, stream>>>(
        ybf, wo_t + (size_t)l * HD * HD, hbuf, nullptr, ab_bf, BT, HD, HD);
    k_ln_router<<<BT, 256, 0, stream>>>(ab_bf, ln2_g + (size_t)l * HD, ln2_b + (size_t)l * HD,
                                        wr_t + (size_t)l * NEXP * HD, lno_bf, gates, eidx);
    k_moesetup2<<<NSB, 1024, 0, stream>>>(eidx, gates, counts, offs,
                                          row_slot, gate_slot, slot_of);
    // grouped experts: 10 routed + shared(#10), one up + one down GEMM
    k_mgemm_moe64<1><<<dim3(8, 160), 256, 0, stream>>>(
        lno_bf, wu_t + (size_t)l * NEXPA * HD * ED, rup_bf,
        counts, offs, row_slot, gate_slot, ED, HD, 1);
    k_mgemm_moe64<3><<<dim3(16, 160), 256, 0, stream>>>(
        rup_bf, wd_t + (size_t)l * NEXPA * ED * HD, rd_bf,
        counts, offs, row_slot, gate_slot, HD, ED, 0);
    if (l < NLAYER - 1) {
      k_combine_ln<1><<<BT, 256, 0, stream>>>(hbuf, rd_bf, slot_of,
                                              ln1_g + (size_t)(l + 1) * HD,
                                              ln1_b + (size_t)(l + 1) * HD, lno_bf);
    } else {
      k_combine_ln<0><<<BT, 256, 0, stream>>>(hbuf, rd_bf, slot_of,
                                              nullptr, nullptr, nullptr);
    }
  }

  k_lnf<<<4, 256, 0, stream>>>(hbuf, lnf_g, lnf_b, hf);
  k_head<<<NVOCAB / 16, 256, 0, stream>>>(hf, W_emb, out);
}